// Round 1
// baseline (1535.947 us; speedup 1.0000x reference)
//
#include <hip/hip_runtime.h>
#include <cstddef>
#include <cstdint>

#define CDIV(a,b) (((a)+(b)-1)/(b))
#define NEG_SLOPE 0.2f

// ---------- monotonic float<->uint encoding for atomicMax on floats ----------
__device__ __forceinline__ unsigned enc_f(float x){
  unsigned u = __float_as_uint(x);
  return (u & 0x80000000u) ? ~u : (u | 0x80000000u);
}
__device__ __forceinline__ float dec_f(unsigned k){
  unsigned u = (k & 0x80000000u) ? (k & 0x7FFFFFFFu) : ~k;
  return __uint_as_float(u);
}

// ---------- generic f32 GEMM: C[M,N] = A[M,K] @ B (+bias) (+=C) ----------
// TRANSB=false: B is [K,N] row-major.  TRANSB=true: B is [N,K] row-major (B^T applied).
// Requires N%64==0, K%16==0. M arbitrary (guarded).
template<bool TRANSB, bool ACCUM>
__global__ __launch_bounds__(256) void gemm64(const float* __restrict__ A,
    const float* __restrict__ B, float* __restrict__ C,
    const float* __restrict__ bias, int M, int N, int K){
  __shared__ float As[16][68];
  __shared__ float Bs[16][68];
  const int tid = threadIdx.x;
  const int bm = blockIdx.y * 64, bn = blockIdx.x * 64;
  const int tx = tid & 15, ty = tid >> 4;
  float acc[4][4];
  #pragma unroll
  for (int i=0;i<4;i++)
    #pragma unroll
    for (int j=0;j<4;j++) acc[i][j]=0.f;

  const int ar = tid >> 2;          // 0..63 (A tile row)
  const int ak = (tid & 3) << 2;    // 0,4,8,12 (A tile k)
  for (int k0=0; k0<K; k0+=16){
    float4 av = make_float4(0.f,0.f,0.f,0.f);
    int arow = bm + ar;
    if (arow < M) av = *(const float4*)(A + (size_t)arow*K + k0 + ak);
    As[ak+0][ar]=av.x; As[ak+1][ar]=av.y; As[ak+2][ar]=av.z; As[ak+3][ar]=av.w;
    if (!TRANSB){
      const int bk = tid >> 4;        // 0..15
      const int bc = (tid & 15) << 2; // 0..60
      float4 bv = *(const float4*)(B + (size_t)(k0+bk)*N + bn + bc);
      Bs[bk][bc+0]=bv.x; Bs[bk][bc+1]=bv.y; Bs[bk][bc+2]=bv.z; Bs[bk][bc+3]=bv.w;
    } else {
      const int bnn = tid >> 2;       // 0..63 (n within tile)
      const int bk  = (tid & 3) << 2; // 0,4,8,12
      float4 bv = *(const float4*)(B + (size_t)(bn+bnn)*K + k0 + bk);
      Bs[bk+0][bnn]=bv.x; Bs[bk+1][bnn]=bv.y; Bs[bk+2][bnn]=bv.z; Bs[bk+3][bnn]=bv.w;
    }
    __syncthreads();
    #pragma unroll
    for (int k=0;k<16;k++){
      float a0=As[k][ty*4+0], a1=As[k][ty*4+1], a2=As[k][ty*4+2], a3=As[k][ty*4+3];
      float b0=Bs[k][tx*4+0], b1=Bs[k][tx*4+1], b2=Bs[k][tx*4+2], b3=Bs[k][tx*4+3];
      acc[0][0]+=a0*b0; acc[0][1]+=a0*b1; acc[0][2]+=a0*b2; acc[0][3]+=a0*b3;
      acc[1][0]+=a1*b0; acc[1][1]+=a1*b1; acc[1][2]+=a1*b2; acc[1][3]+=a1*b3;
      acc[2][0]+=a2*b0; acc[2][1]+=a2*b1; acc[2][2]+=a2*b2; acc[2][3]+=a2*b3;
      acc[3][0]+=a3*b0; acc[3][1]+=a3*b1; acc[3][2]+=a3*b2; acc[3][3]+=a3*b3;
    }
    __syncthreads();
  }
  #pragma unroll
  for (int i=0;i<4;i++){
    int row = bm + ty*4 + i;
    if (row >= M) continue;
    float* cp = C + (size_t)row*N + bn + tx*4;
    float4 v = make_float4(acc[i][0],acc[i][1],acc[i][2],acc[i][3]);
    if (bias){
      const float4 b4 = *(const float4*)(bias + bn + tx*4);
      v.x+=b4.x; v.y+=b4.y; v.z+=b4.z; v.w+=b4.w;
    }
    if (ACCUM){
      float4 c4 = *(const float4*)cp;
      v.x+=c4.x; v.y+=c4.y; v.z+=c4.z; v.w+=c4.w;
    }
    *(float4*)cp = v;
  }
}

// ---------- alpha[m] = sum_k X[m,256]*a[k] : one wave per row ----------
__global__ __launch_bounds__(256) void rowdot(const float* __restrict__ X,
    const float* __restrict__ a, float* __restrict__ out, int M){
  int wid = threadIdx.x >> 6, lane = threadIdx.x & 63;
  int row = blockIdx.x*4 + wid;
  if (row >= M) return;
  float4 x4 = *(const float4*)(X + (size_t)row*256 + lane*4);
  float4 a4 = *(const float4*)(a + lane*4);
  float v = x4.x*a4.x + x4.y*a4.y + x4.z*a4.z + x4.w*a4.w;
  #pragma unroll
  for (int off=32; off; off>>=1) v += __shfl_down(v, off);
  if (lane==0) out[row]=v;
}

// ---------- edge pass A: alpha, segment-max (encoded), degree count ----------
__global__ __launch_bounds__(256) void edge_a(const int* __restrict__ src,
    const int* __restrict__ dst, const float* __restrict__ as,
    const float* __restrict__ ad, float* __restrict__ alpha_e,
    unsigned* __restrict__ amax, int* __restrict__ cnt, int E){
  int e = blockIdx.x*256 + threadIdx.x;
  if (e >= E) return;
  int s = src[e], d = dst[e];
  float al = as[s] + ad[d];
  al = al > 0.f ? al : NEG_SLOPE*al;
  alpha_e[e] = al;
  atomicMax(&amax[d], enc_f(al));
  atomicAdd(&cnt[d], 1);
}

// self-loops: alpha_self[j], fold into segment max
__global__ __launch_bounds__(256) void self_a(const float* __restrict__ as,
    const float* __restrict__ ad, float* __restrict__ alpha_self,
    unsigned* __restrict__ amax, int n){
  int j = blockIdx.x*256 + threadIdx.x;
  if (j >= n) return;
  float al = as[j] + ad[j];
  al = al > 0.f ? al : NEG_SLOPE*al;
  alpha_self[j] = al;
  atomicMax(&amax[j], enc_f(al));
}

// ---------- single-block exclusive scan of cnt -> base, cursor ----------
__global__ __launch_bounds__(256) void scan_k(const int* __restrict__ cnt,
    int* __restrict__ base, int* __restrict__ cursor, int n){
  __shared__ int buf[256];
  __shared__ int carry;
  if (threadIdx.x==0) carry = 0;
  __syncthreads();
  for (int start=0; start<n; start+=256){
    int i = start + threadIdx.x;
    int v = (i<n) ? cnt[i] : 0;
    buf[threadIdx.x]=v;
    __syncthreads();
    #pragma unroll
    for (int off=1; off<256; off<<=1){
      int t = (threadIdx.x>=off) ? buf[threadIdx.x-off] : 0;
      __syncthreads();
      buf[threadIdx.x]+=t;
      __syncthreads();
    }
    int cbase = carry;
    int excl = buf[threadIdx.x] - v + cbase;
    if (i<n){ base[i]=excl; cursor[i]=excl; }
    __syncthreads();
    if (threadIdx.x==0) carry = cbase + buf[255];
    __syncthreads();
  }
}

// ---------- edge pass B: e=exp(alpha-amax), CSR fill ----------
__global__ __launch_bounds__(256) void edge_b(const int* __restrict__ src,
    const int* __restrict__ dst, const float* __restrict__ alpha_e,
    const unsigned* __restrict__ amax, int* __restrict__ cursor,
    int* __restrict__ csr_src, float* __restrict__ csr_e, int E){
  int e = blockIdx.x*256 + threadIdx.x;
  if (e >= E) return;
  int d = dst[e];
  float ev = expf(alpha_e[e] - dec_f(amax[d]));
  int pos = atomicAdd(&cursor[d], 1);
  csr_src[pos] = src[e];
  csr_e[pos] = ev;
}

// ---------- gather + softmax-normalize + bias + tanh : one wave per dst ----------
__global__ __launch_bounds__(256) void gather_xb(const float* __restrict__ xs,
    const int* __restrict__ base, const int* __restrict__ cnt,
    const int* __restrict__ csr_src, const float* __restrict__ csr_e,
    const float* __restrict__ alpha_self, const unsigned* __restrict__ amax,
    const float* __restrict__ gb, float* __restrict__ xb, int n){
  int wid = threadIdx.x >> 6, lane = threadIdx.x & 63;
  int j = blockIdx.x*4 + wid;
  if (j >= n) return;
  int b0 = base[j], cn = cnt[j];
  float ax=0.f, ay=0.f, az=0.f, aw=0.f, dsum=0.f;
  for (int k=0;k<cn;k++){
    int s = csr_src[b0+k];
    float ev = csr_e[b0+k];
    float4 x4 = *(const float4*)(xs + (size_t)s*256 + lane*4);
    ax += ev*x4.x; ay += ev*x4.y; az += ev*x4.z; aw += ev*x4.w;
    dsum += ev;
  }
  // self loop
  float es = expf(alpha_self[j] - dec_f(amax[j]));
  {
    float4 x4 = *(const float4*)(xs + (size_t)j*256 + lane*4);
    ax += es*x4.x; ay += es*x4.y; az += es*x4.z; aw += es*x4.w;
    dsum += es;
  }
  float inv = 1.f/dsum;
  float4 g4 = *(const float4*)(gb + lane*4);
  float4 o;
  o.x = tanhf(ax*inv + g4.x);
  o.y = tanhf(ay*inv + g4.y);
  o.z = tanhf(az*inv + g4.z);
  o.w = tanhf(aw*inv + g4.w);
  *(float4*)(xb + (size_t)j*256 + lane*4) = o;
}

// ---------- LSTM activation ----------
__global__ __launch_bounds__(256) void lstm_act(const float* __restrict__ gates,
    float* __restrict__ h, float* __restrict__ c, int n_dst, int first){
  int idx = blockIdx.x*256 + threadIdx.x;
  if (idx >= n_dst*256) return;
  int row = idx >> 8, ch = idx & 255;
  const float* g = gates + (size_t)row*1024;
  float gi = g[ch], gf = g[ch+256], gg = g[ch+512], go = g[ch+768];
  float si = 1.f/(1.f+expf(-gi));
  float so = 1.f/(1.f+expf(-go));
  float tg = tanhf(gg);
  float cn;
  if (first) cn = si*tg;
  else {
    float sf = 1.f/(1.f+expf(-gf));
    cn = sf*c[idx] + si*tg;
  }
  float hn = so*tanhf(cn);
  c[idx] = cn;
  h[idx] = hn;
}

extern "C" void kernel_launch(void* const* d_in, const int* in_sizes, int n_in,
                              void* d_out, int out_size, void* d_ws, size_t ws_size,
                              hipStream_t stream){
  const float* feats   = (const float*)d_in[0];
  const float* Win     = (const float*)d_in[1];
  const float* b_in    = (const float*)d_in[2];
  const float* Wsrc    = (const float*)d_in[3];
  const float* Wdst    = (const float*)d_in[4];
  const float* att_src = (const float*)d_in[5];
  const float* att_dst = (const float*)d_in[6];
  const float* gat_b   = (const float*)d_in[7];
  const float* W_ih    = (const float*)d_in[8];
  const float* W_hh    = (const float*)d_in[9];
  const float* Wout    = (const float*)d_in[10];
  const float* b_out   = (const float*)d_in[11];
  const int* srcs[3] = {(const int*)d_in[12], (const int*)d_in[14], (const int*)d_in[16]};
  const int* dsts[3] = {(const int*)d_in[13], (const int*)d_in[15], (const int*)d_in[17]};

  const int n_src_a[3] = {60000,30000,15000};
  const int n_dst_a[3] = {30000,15000,7500};
  const int E_a[3]     = {480000,240000,120000};
  const int H = 256;

  // ---- workspace layout (~253 MB) ----
  char* w = (char*)d_ws;
  auto alloc = [&](size_t b)->char*{ char* p = w; w += (b + 255) & ~(size_t)255; return p; };
  float* x0 = (float*)alloc(60000ull*256*4);   // 61.44 MB : hop-0 input x
  float* xs = (float*)alloc(60000ull*256*4);   // 61.44 MB
  float* gates = x0;                           // aliases x0+xs (122.88 MB, both dead by then)
  float* xd = (float*)alloc(30000ull*256*4);
  float* xb = (float*)alloc(30000ull*256*4);
  float* h  = (float*)alloc(30000ull*256*4);
  float* c  = (float*)alloc(30000ull*256*4);
  float* alpha_s    = (float*)alloc(60000ull*4);
  float* alpha_d    = (float*)alloc(30000ull*4);
  float* alpha_e    = (float*)alloc(480000ull*4);
  float* alpha_self = (float*)alloc(30000ull*4);
  unsigned* amax = (unsigned*)alloc(30000ull*4);
  int* cnt    = (int*)alloc(30000ull*4);
  int* base   = (int*)alloc(30000ull*4);
  int* cursor = (int*)alloc(30000ull*4);
  int* csr_src = (int*)alloc(480000ull*4);
  float* csr_e = (float*)alloc(480000ull*4);
  (void)ws_size; (void)in_sizes; (void)n_in; (void)out_size;

  // input projection: x0 = feats @ Win + b_in   [60000,128]@[128,256]
  {
    dim3 g(256/64, CDIV(60000,64));
    gemm64<false,false><<<g, 256, 0, stream>>>(feats, Win, x0, b_in, 60000, 256, 128);
  }

  const float* x = x0;
  for (int hop=0; hop<3; hop++){
    const int ns = n_src_a[hop], nd = n_dst_a[hop], E = E_a[hop];
    hipMemsetAsync(amax, 0, (size_t)nd*4, stream);
    hipMemsetAsync(cnt,  0, (size_t)nd*4, stream);

    dim3 gs(256/64, CDIV(ns,64));
    gemm64<false,false><<<gs, 256, 0, stream>>>(x, Wsrc + (size_t)hop*H*H, xs, nullptr, ns, 256, 256);
    dim3 gd(256/64, CDIV(nd,64));
    gemm64<false,false><<<gd, 256, 0, stream>>>(x, Wdst + (size_t)hop*H*H, xd, nullptr, nd, 256, 256);

    rowdot<<<CDIV(ns,4), 256, 0, stream>>>(xs, att_src + hop*H, alpha_s, ns);
    rowdot<<<CDIV(nd,4), 256, 0, stream>>>(xd, att_dst + hop*H, alpha_d, nd);

    edge_a<<<CDIV(E,256), 256, 0, stream>>>(srcs[hop], dsts[hop], alpha_s, alpha_d,
                                            alpha_e, amax, cnt, E);
    self_a<<<CDIV(nd,256), 256, 0, stream>>>(alpha_s, alpha_d, alpha_self, amax, nd);
    scan_k<<<1, 256, 0, stream>>>(cnt, base, cursor, nd);
    edge_b<<<CDIV(E,256), 256, 0, stream>>>(srcs[hop], dsts[hop], alpha_e, amax,
                                            cursor, csr_src, csr_e, E);
    gather_xb<<<CDIV(nd,4), 256, 0, stream>>>(xs, base, cnt, csr_src, csr_e,
                                              alpha_self, amax, gat_b + hop*H, xb, nd);

    // LSTM gates = xb @ W_ih^T (+ h @ W_hh^T for hop>0)
    dim3 gg(1024/64, CDIV(nd,64));
    gemm64<true,false><<<gg, 256, 0, stream>>>(xb, W_ih + (size_t)hop*4*H*H, gates, nullptr, nd, 1024, 256);
    if (hop > 0)
      gemm64<true,true><<<gg, 256, 0, stream>>>(h, W_hh + (size_t)hop*4*H*H, gates, nullptr, nd, 1024, 256);
    lstm_act<<<CDIV(nd*256,256), 256, 0, stream>>>(gates, h, c, nd, hop==0 ? 1 : 0);
    x = h;
  }

  // output projection: d_out = h @ Wout + b_out   [7500,256]@[256,128]
  {
    dim3 g(128/64, CDIV(7500,64));
    gemm64<false,false><<<g, 256, 0, stream>>>(h, Wout, (float*)d_out, b_out, 7500, 128, 256);
  }
}

// Round 2
// 927.478 us; speedup vs baseline: 1.6560x; 1.6560x over previous
//
#include <hip/hip_runtime.h>
#include <cstddef>
#include <cstdint>

#define CDIV(a,b) (((a)+(b)-1)/(b))
#define NEG_SLOPE 0.2f

typedef unsigned short u16;
typedef __attribute__((ext_vector_type(8))) short bf16x8;
typedef __attribute__((ext_vector_type(4))) float f32x4;

// ---------- bf16 helpers (explicit RNE, hi/lo split: v ~= hi + lo, ~17 mantissa bits) ----------
__device__ __forceinline__ u16 bf16_rne(float v){
  unsigned u = __float_as_uint(v);
  unsigned r = (u + 0x7FFFu + ((u >> 16) & 1u)) >> 16;
  return (u16)r;
}
__device__ __forceinline__ float bf16_to_f(u16 h){
  return __uint_as_float(((unsigned)h) << 16);
}
__device__ __forceinline__ void f2hilo(float v, u16& h, u16& l){
  h = bf16_rne(v);
  float r = v - bf16_to_f(h);
  l = bf16_rne(r);
}

// ---------- monotonic float<->uint encoding for atomicMax on floats ----------
__device__ __forceinline__ unsigned enc_f(float x){
  unsigned u = __float_as_uint(x);
  return (u & 0x80000000u) ? ~u : (u | 0x80000000u);
}
__device__ __forceinline__ float dec_f(unsigned k){
  unsigned u = (k & 0x80000000u) ? (k & 0x7FFFFFFFu) : ~k;
  return __uint_as_float(u);
}

// ---------- async global->LDS, 16B per lane ----------
__device__ __forceinline__ void gload16(const void* g, void* l){
  __builtin_amdgcn_global_load_lds((const __attribute__((address_space(1))) void*)g,
                                   (__attribute__((address_space(3))) void*)l, 16, 0, 0);
}

// =====================================================================================
// MFMA GEMM: C[M,N] = sum over pairs q, phases p of Aq_p[M,K] @ Bq_p[N,K]^T
// Phases implement the hi/lo split: Ah*Bh + Al*Bh + Ah*Bl  (f32-accuracy from bf16 MFMA).
// B is stored TRANSPOSED ([N][K] row-major bf16). N%128==0, K%64==0, M arbitrary.
// 128x128 tile, 4 waves (each 64x64 via 4x4 frags of 16x16x32), BK=64.
// LDS tiles [128 rows][64 elems] bf16 with XOR slot swizzle (slot ^= row&7) applied by
// pre-swizzling the *global* source address (global_load_lds dest must stay linear, m173).
// Fragment ds_read_b128 is then bank-conflict-free.
// =====================================================================================
__global__ __launch_bounds__(256, 2) void mfma_gemm(
    const u16* __restrict__ Ah0, const u16* __restrict__ Al0,
    const u16* __restrict__ Bh0, const u16* __restrict__ Bl0,
    const u16* __restrict__ Ah1, const u16* __restrict__ Al1,
    const u16* __restrict__ Bh1, const u16* __restrict__ Bl1,
    int npairs, int M, int N, int K,
    const float* __restrict__ bias, float* __restrict__ C,
    u16* __restrict__ outHi, u16* __restrict__ outLo)
{
  __shared__ u16 smem[2 * 8192];  // A tile @0, B tile @8192 (each 128x64 bf16 = 16KB)
  const int tid = threadIdx.x;
  const int lane = tid & 63, wv = tid >> 6;
  const int l15 = lane & 15, lq = lane >> 4;
  const int wr = wv >> 1, wc = wv & 1;
  const int bm = blockIdx.y * 128, bn = blockIdx.x * 128;
  const int rmA = M - bm;  // >= 1

  f32x4 acc[4][4];
  #pragma unroll
  for (int m = 0; m < 4; m++)
    #pragma unroll
    for (int n = 0; n < 4; n++) acc[m][n] = (f32x4){0.f, 0.f, 0.f, 0.f};

  // staging geometry: chunk c = i*256+tid covers LDS bytes c*16; row=c>>3, phys slot c&7,
  // logical slot s = (c&7) ^ (row&7)  (inverse-swizzled global source)
  int srow[4], sslot[4], ldso[4];
  #pragma unroll
  for (int i = 0; i < 4; i++){
    int c = i * 256 + tid;
    srow[i]  = c >> 3;
    sslot[i] = (c & 7) ^ (srow[i] & 7);
    ldso[i]  = (i * 256 + (tid & 192)) * 8;  // wave-uniform base, ushort units
  }

  for (int q = 0; q < npairs; q++){
    const u16* Ah = q ? Ah1 : Ah0;  const u16* Al = q ? Al1 : Al0;
    const u16* Bh = q ? Bh1 : Bh0;  const u16* Bl = q ? Bl1 : Bl0;
    #pragma unroll 1
    for (int p = 0; p < 3; p++){
      const u16* A = (p == 1) ? Al : Ah;
      const u16* B = (p == 2) ? Bl : Bh;
      #pragma unroll 1
      for (int k0 = 0; k0 < K; k0 += 64){
        #pragma unroll
        for (int i = 0; i < 4; i++){
          int gr = srow[i] < rmA ? srow[i] : rmA - 1;  // clamp tail rows (garbage->unstored)
          gload16(A + (size_t)(bm + gr) * K + k0 + sslot[i] * 8, smem + ldso[i]);
        }
        #pragma unroll
        for (int i = 0; i < 4; i++){
          gload16(B + (size_t)(bn + srow[i]) * K + k0 + sslot[i] * 8, smem + 8192 + ldso[i]);
        }
        __syncthreads();  // compiler emits vmcnt(0) drain -> LDS valid
        #pragma unroll
        for (int kb = 0; kb < 8; kb += 4){
          bf16x8 af[4], bfr[4];
          #pragma unroll
          for (int m = 0; m < 4; m++){
            int r = wr * 64 + m * 16 + l15;
            int s = (kb + lq) ^ (r & 7);
            af[m] = *(const bf16x8*)(smem + r * 64 + s * 8);
          }
          #pragma unroll
          for (int n = 0; n < 4; n++){
            int r = wc * 64 + n * 16 + l15;
            int s = (kb + lq) ^ (r & 7);
            bfr[n] = *(const bf16x8*)(smem + 8192 + r * 64 + s * 8);
          }
          #pragma unroll
          for (int m = 0; m < 4; m++)
            #pragma unroll
            for (int n = 0; n < 4; n++)
              acc[m][n] = __builtin_amdgcn_mfma_f32_16x16x32_bf16(af[m], bfr[n], acc[m][n], 0, 0, 0);
        }
        __syncthreads();
      }
    }
  }

  // epilogue: C/D layout col=lane&15, row=(lane>>4)*4+j (m89/m91-verified)
  const int rb = bm + wr * 64 + lq * 4;
  const int cb = bn + wc * 64 + l15;
  #pragma unroll
  for (int n = 0; n < 4; n++){
    int col = cb + n * 16;
    float bv = bias ? bias[col] : 0.f;
    #pragma unroll
    for (int m = 0; m < 4; m++){
      int row0 = rb + m * 16;
      #pragma unroll
      for (int j = 0; j < 4; j++){
        int row = row0 + j;
        if (row < M){
          float v = acc[m][n][j] + bv;
          size_t off = (size_t)row * N + col;
          if (C) C[off] = v;
          if (outHi){
            u16 hh, hl; f2hilo(v, hh, hl);
            outHi[off] = hh; outLo[off] = hl;
          }
        }
      }
    }
  }
}

// ---------- feats f32 -> hi/lo bf16, 4 elems/thread ----------
__global__ __launch_bounds__(256) void cvt_feats(const float* __restrict__ in,
    u16* __restrict__ hi, u16* __restrict__ lo, int n4){
  int i = blockIdx.x * 256 + threadIdx.x;
  if (i >= n4) return;
  float4 v = *(const float4*)(in + (size_t)i * 4);
  ushort4 h4, l4;
  f2hilo(v.x, h4.x, l4.x); f2hilo(v.y, h4.y, l4.y);
  f2hilo(v.z, h4.z, l4.z); f2hilo(v.w, h4.w, l4.w);
  *(ushort4*)(hi + (size_t)i * 4) = h4;
  *(ushort4*)(lo + (size_t)i * 4) = l4;
}

// ---------- one-shot weight prep: transpose where needed, convert to hi/lo bf16 [N][K] ----------
__global__ __launch_bounds__(256) void prep_w(const float* __restrict__ Win,
    const float* __restrict__ Wsrc, const float* __restrict__ Wih,
    const float* __restrict__ Whh, const float* __restrict__ Wout,
    u16* WinH, u16* WinL, u16* WsH, u16* WsL,
    u16* IhH, u16* IhL, u16* HhH, u16* HhL, u16* WoH, u16* WoL){
  int idx = blockIdx.x * 256 + threadIdx.x;
  float v; u16 *ph, *pl; int off;
  if (idx < 32768){                       // WinT [256][128] <- Win[128][256]
    int n = idx >> 7, k = idx & 127;
    v = Win[k * 256 + n]; ph = WinH; pl = WinL; off = idx;
  } else if (idx < 229376){               // WsrcT [3][256][256] <- Wsrc[3][256][256]^T
    int t = idx - 32768; int hop = t >> 16, r = t & 65535, n = r >> 8, k = r & 255;
    v = Wsrc[hop * 65536 + k * 256 + n]; ph = WsH; pl = WsL; off = t;
  } else if (idx < 1015808){              // W_ih [3][1024][256] already [N][K]
    int t = idx - 229376; v = Wih[t]; ph = IhH; pl = IhL; off = t;
  } else if (idx < 1802240){              // W_hh
    int t = idx - 1015808; v = Whh[t]; ph = HhH; pl = HhL; off = t;
  } else if (idx < 1835008){              // WoutT [128][256] <- Wout[256][128]
    int t = idx - 1802240; int n = t >> 8, k = t & 255;
    v = Wout[k * 128 + n]; ph = WoH; pl = WoL; off = t;
  } else return;
  u16 hh, hl; f2hilo(v, hh, hl);
  ph[off] = hh; pl[off] = hl;
}

// ---------- w_s[hop] = Wsrc[hop]@a_s, w_d[hop] = Wdst[hop]@a_d (row dots, f32) ----------
__global__ __launch_bounds__(256) void prep_wvec(const float* __restrict__ Wsrc,
    const float* __restrict__ Wdst, const float* __restrict__ as_,
    const float* __restrict__ ad_, float* __restrict__ wsv, float* __restrict__ wdv){
  int wid = blockIdx.x * 4 + (threadIdx.x >> 6), lane = threadIdx.x & 63;
  if (wid >= 6 * 256) return;
  int vec = wid >> 8, i = wid & 255;
  int hop = vec >> 1; bool isd = vec & 1;
  const float* Wrow = (isd ? Wdst : Wsrc) + (size_t)hop * 65536 + (size_t)i * 256;
  const float* a = (isd ? ad_ : as_) + hop * 256;
  float4 w4 = *(const float4*)(Wrow + lane * 4);
  float4 a4 = *(const float4*)(a + lane * 4);
  float v = w4.x * a4.x + w4.y * a4.y + w4.z * a4.z + w4.w * a4.w;
  #pragma unroll
  for (int off = 32; off; off >>= 1) v += __shfl_down(v, off);
  if (!lane) (isd ? wdv : wsv)[hop * 256 + i] = v;
}

// ---------- alpha_s[m]=x[m]@w_s, alpha_d[m]=x[m]@w_d from hi/lo x; one wave/row ----------
__global__ __launch_bounds__(256) void alpha_mv(const u16* __restrict__ xh,
    const u16* __restrict__ xl, const float* __restrict__ wsv, const float* __restrict__ wdv,
    float* __restrict__ as_out, float* __restrict__ ad_out, int ns, int nd){
  int wid = blockIdx.x * 4 + (threadIdx.x >> 6), lane = threadIdx.x & 63;
  if (wid >= ns + nd) return;
  bool isd = wid >= ns;
  int row = isd ? wid - ns : wid;
  ushort4 vh = *(const ushort4*)(xh + (size_t)row * 256 + lane * 4);
  ushort4 vl = *(const ushort4*)(xl + (size_t)row * 256 + lane * 4);
  const float* wv = isd ? wdv : wsv;
  float4 w4 = *(const float4*)(wv + lane * 4);
  float v = (bf16_to_f(vh.x) + bf16_to_f(vl.x)) * w4.x
          + (bf16_to_f(vh.y) + bf16_to_f(vl.y)) * w4.y
          + (bf16_to_f(vh.z) + bf16_to_f(vl.z)) * w4.z
          + (bf16_to_f(vh.w) + bf16_to_f(vl.w)) * w4.w;
  #pragma unroll
  for (int off = 32; off; off >>= 1) v += __shfl_down(v, off);
  if (!lane) (isd ? ad_out : as_out)[row] = v;
}

// ---------- edges + self-loops: leaky-relu alpha, segment max (encoded), degree ----------
__global__ __launch_bounds__(256) void edge_a(const int* __restrict__ src,
    const int* __restrict__ dst, const float* __restrict__ as_, const float* __restrict__ ad_,
    float* __restrict__ alpha_e, float* __restrict__ alpha_self,
    unsigned* __restrict__ amax, int* __restrict__ cnt, int E, int nd){
  int i = blockIdx.x * 256 + threadIdx.x;
  if (i < E){
    int s = src[i], d = dst[i];
    float al = as_[s] + ad_[d];
    al = al > 0.f ? al : NEG_SLOPE * al;
    alpha_e[i] = al;
    atomicMax(&amax[d], enc_f(al));
    atomicAdd(&cnt[d], 1);
  } else if (i < E + nd){
    int j = i - E;
    float al = as_[j] + ad_[j];
    al = al > 0.f ? al : NEG_SLOPE * al;
    alpha_self[j] = al;
    atomicMax(&amax[j], enc_f(al));
  }
}

// ---------- single-block exclusive scan (wave-shfl, 3 barriers/chunk) ----------
__global__ __launch_bounds__(256) void scan_k(const int* __restrict__ cnt,
    int* __restrict__ base, int* __restrict__ cursor, int n){
  __shared__ int wtot[4];
  __shared__ int carry;
  int lane = threadIdx.x & 63, wv = threadIdx.x >> 6;
  if (threadIdx.x == 0) carry = 0;
  __syncthreads();
  for (int start = 0; start < n; start += 256){
    int i = start + threadIdx.x;
    int v = (i < n) ? cnt[i] : 0;
    int incl = v;
    #pragma unroll
    for (int off = 1; off < 64; off <<= 1){
      int t = __shfl_up(incl, off);
      if (lane >= off) incl += t;
    }
    if (lane == 63) wtot[wv] = incl;
    __syncthreads();
    int woff = carry;
    for (int w = 0; w < wv; w++) woff += wtot[w];
    int excl = woff + incl - v;
    if (i < n){ base[i] = excl; cursor[i] = excl; }
    __syncthreads();
    if (threadIdx.x == 0) carry += wtot[0] + wtot[1] + wtot[2] + wtot[3];
    __syncthreads();
  }
}

// ---------- e=exp(alpha-amax), CSR fill ----------
__global__ __launch_bounds__(256) void edge_b(const int* __restrict__ src,
    const int* __restrict__ dst, const float* __restrict__ alpha_e,
    const unsigned* __restrict__ amax, int* __restrict__ cursor,
    int* __restrict__ csr_src, float* __restrict__ csr_e, int E){
  int e = blockIdx.x * 256 + threadIdx.x;
  if (e >= E) return;
  int d = dst[e];
  float ev = expf(alpha_e[e] - dec_f(amax[d]));
  int pos = atomicAdd(&cursor[d], 1);
  csr_src[pos] = src[e];
  csr_e[pos] = ev;
}

// ---------- gather + normalize + bias + tanh -> xb hi/lo bf16; one wave/dst ----------
__global__ __launch_bounds__(256) void gather_xb(const float* __restrict__ xs,
    const int* __restrict__ base, const int* __restrict__ cnt,
    const int* __restrict__ csr_src, const float* __restrict__ csr_e,
    const float* __restrict__ alpha_self, const unsigned* __restrict__ amax,
    const float* __restrict__ gb, u16* __restrict__ xbH, u16* __restrict__ xbL, int n){
  int wv = threadIdx.x >> 6, lane = threadIdx.x & 63;
  int j = blockIdx.x * 4 + wv;
  if (j >= n) return;
  int b0 = base[j], cn = cnt[j];
  float ax = 0.f, ay = 0.f, az = 0.f, aw = 0.f, ds = 0.f;
  for (int k = 0; k < cn; k++){
    int s = csr_src[b0 + k];
    float ev = csr_e[b0 + k];
    float4 x4 = *(const float4*)(xs + (size_t)s * 256 + lane * 4);
    ax += ev * x4.x; ay += ev * x4.y; az += ev * x4.z; aw += ev * x4.w; ds += ev;
  }
  float es = expf(alpha_self[j] - dec_f(amax[j]));
  float4 x4 = *(const float4*)(xs + (size_t)j * 256 + lane * 4);
  ax += es * x4.x; ay += es * x4.y; az += es * x4.z; aw += es * x4.w; ds += es;
  float inv = 1.f / ds;
  float4 g4 = *(const float4*)(gb + lane * 4);
  float o0 = tanhf(ax * inv + g4.x), o1 = tanhf(ay * inv + g4.y);
  float o2 = tanhf(az * inv + g4.z), o3 = tanhf(aw * inv + g4.w);
  ushort4 h4, l4;
  f2hilo(o0, h4.x, l4.x); f2hilo(o1, h4.y, l4.y);
  f2hilo(o2, h4.z, l4.z); f2hilo(o3, h4.w, l4.w);
  *(ushort4*)(xbH + (size_t)j * 256 + lane * 4) = h4;
  *(ushort4*)(xbL + (size_t)j * 256 + lane * 4) = l4;
}

// ---------- LSTM activation; writes c f32 and h as hi/lo bf16 ----------
__global__ __launch_bounds__(256) void lstm_act(const float* __restrict__ gates,
    u16* __restrict__ hH, u16* __restrict__ hL, float* __restrict__ c, int n_dst, int first){
  int idx = blockIdx.x * 256 + threadIdx.x;
  if (idx >= n_dst * 256) return;
  int row = idx >> 8, ch = idx & 255;
  const float* g = gates + (size_t)row * 1024;
  float gi = g[ch], gf = g[ch + 256], gg = g[ch + 512], go = g[ch + 768];
  float si = 1.f / (1.f + expf(-gi));
  float so = 1.f / (1.f + expf(-go));
  float tg = tanhf(gg);
  float cn = first ? si * tg : (1.f / (1.f + expf(-gf))) * c[idx] + si * tg;
  float hn = so * tanhf(cn);
  c[idx] = cn;
  u16 hh, hl; f2hilo(hn, hh, hl);
  hH[idx] = hh; hL[idx] = hl;
}

extern "C" void kernel_launch(void* const* d_in, const int* in_sizes, int n_in,
                              void* d_out, int out_size, void* d_ws, size_t ws_size,
                              hipStream_t stream){
  const float* feats   = (const float*)d_in[0];
  const float* Win     = (const float*)d_in[1];
  const float* b_in    = (const float*)d_in[2];
  const float* Wsrc    = (const float*)d_in[3];
  const float* Wdst    = (const float*)d_in[4];
  const float* att_src = (const float*)d_in[5];
  const float* att_dst = (const float*)d_in[6];
  const float* gat_b   = (const float*)d_in[7];
  const float* W_ih    = (const float*)d_in[8];
  const float* W_hh    = (const float*)d_in[9];
  const float* Wout    = (const float*)d_in[10];
  const float* b_out   = (const float*)d_in[11];
  const int* srcs[3] = {(const int*)d_in[12], (const int*)d_in[14], (const int*)d_in[16]};
  const int* dsts[3] = {(const int*)d_in[13], (const int*)d_in[15], (const int*)d_in[17]};
  (void)in_sizes; (void)n_in; (void)out_size; (void)ws_size;

  const int ns_a[3] = {60000, 30000, 15000};
  const int nd_a[3] = {30000, 15000, 7500};
  const int E_a[3]  = {480000, 240000, 120000};

  // ---- workspace layout (bytes), total ~248 MiB; aliasing is lifetime-checked ----
  char* w = (char*)d_ws;
  // [0, 122.88M): gates f32 (hop0 30000x1024); second half doubles as xs f32
  float* gates = (float*)(w + 0);
  float* xs    = (float*)(w + 61440000);          // [60000][256] f32 (dead before gates write)
  u16* featsH  = (u16*)(w + 61440000);            // aliases xs (dead before xs written)
  u16* featsL  = (u16*)(w + 61440000 + 15360000);
  // [122.88M, 184.32M): x0 hi/lo (hop0 only); later c f32 (written after x0 dead)
  u16* x0H     = (u16*)(w + 122880000);           // [60000][256] bf16
  u16* x0L     = (u16*)(w + 153600000);
  float* c     = (float*)(w + 122880000);         // [30000][256] f32
  u16* hH      = (u16*)(w + 184320000);           // [30000][256] bf16
  u16* hL      = (u16*)(w + 199680000);
  u16* xbH     = (u16*)(w + 215040000);
  u16* xbL     = (u16*)(w + 230400000);
  // weights hi/lo (B^T form [N][K]) + att matvecs
  u16* WinH = (u16*)(w + 245760000);  u16* WinL = WinH + 32768;
  u16* WsH  = WinL + 32768;           u16* WsL  = WsH + 196608;
  u16* IhH  = WsL + 196608;           u16* IhL  = IhH + 786432;
  u16* HhH  = IhL + 786432;           u16* HhL  = HhH + 786432;
  u16* WoH  = HhL + 786432;           u16* WoL  = WoH + 32768;
  float* wsv = (float*)(WoL + 32768); float* wdv = wsv + 768;
  // misc
  float* alpha_s    = (float*)(w + 253106176);
  float* alpha_d    = alpha_s + 60000;
  float* alpha_e    = alpha_d + 30000;
  float* alpha_self = alpha_e + 480000;
  unsigned* amax    = (unsigned*)(alpha_self + 30000);
  int* cnt          = (int*)(amax + 30000);
  int* base         = cnt + 30000;
  int* cursor       = base + 30000;
  int* csr_src      = cursor + 30000;
  float* csr_e      = (float*)(csr_src + 480000);

  // ---- one-time prep (inputs only) ----
  prep_w<<<7168, 256, 0, stream>>>(Win, Wsrc, W_ih, W_hh, Wout,
      WinH, WinL, WsH, WsL, IhH, IhL, HhH, HhL, WoH, WoL);
  prep_wvec<<<384, 256, 0, stream>>>(Wsrc, Wdst, att_src, att_dst, wsv, wdv);
  cvt_feats<<<7500, 256, 0, stream>>>(feats, featsH, featsL, 1920000);

  // ---- input projection: x0(hi/lo) = feats @ Win + b_in ----
  {
    dim3 g(2, CDIV(60000, 128));
    mfma_gemm<<<g, 256, 0, stream>>>(featsH, featsL, WinH, WinL,
        nullptr, nullptr, nullptr, nullptr, 1, 60000, 256, 128,
        b_in, nullptr, x0H, x0L);
  }

  const u16* xHp = x0H; const u16* xLp = x0L;
  for (int hop = 0; hop < 3; hop++){
    const int ns = ns_a[hop], nd = nd_a[hop], E = E_a[hop];
    hipMemsetAsync(amax, 0, (size_t)(30000 + nd) * 4, stream);  // amax[30000] + cnt[0..nd)

    // xs = x @ Wsrc[hop]   (f32 out, feeds gather)
    {
      dim3 g(2, CDIV(ns, 128));
      mfma_gemm<<<g, 256, 0, stream>>>(xHp, xLp, WsH + (size_t)hop * 65536, WsL + (size_t)hop * 65536,
          nullptr, nullptr, nullptr, nullptr, 1, ns, 256, 256,
          nullptr, xs, nullptr, nullptr);
    }
    alpha_mv<<<CDIV(ns + nd, 4), 256, 0, stream>>>(xHp, xLp, wsv + hop * 256, wdv + hop * 256,
        alpha_s, alpha_d, ns, nd);
    edge_a<<<CDIV(E + nd, 256), 256, 0, stream>>>(srcs[hop], dsts[hop], alpha_s, alpha_d,
        alpha_e, alpha_self, amax, cnt, E, nd);
    scan_k<<<1, 256, 0, stream>>>(cnt, base, cursor, nd);
    edge_b<<<CDIV(E, 256), 256, 0, stream>>>(srcs[hop], dsts[hop], alpha_e, amax,
        cursor, csr_src, csr_e, E);
    gather_xb<<<CDIV(nd, 4), 256, 0, stream>>>(xs, base, cnt, csr_src, csr_e,
        alpha_self, amax, gat_b + hop * 256, xbH, xbL, nd);

    // gates = xb @ W_ih^T (+ h @ W_hh^T for hop>0), fused as two operand pairs
    {
      dim3 g(8, CDIV(nd, 128));
      mfma_gemm<<<g, 256, 0, stream>>>(xbH, xbL, IhH + (size_t)hop * 262144, IhL + (size_t)hop * 262144,
          hH, hL, HhH + (size_t)hop * 262144, HhL + (size_t)hop * 262144,
          hop ? 2 : 1, nd, 1024, 256,
          nullptr, gates, nullptr, nullptr);
    }
    lstm_act<<<CDIV(nd * 256, 256), 256, 0, stream>>>(gates, hH, hL, c, nd, hop == 0 ? 1 : 0);
    xHp = hH; xLp = hL;
  }

  // ---- output projection: d_out = h @ Wout + b_out ----
  {
    dim3 g(1, CDIV(7500, 128));
    mfma_gemm<<<g, 256, 0, stream>>>(hH, hL, WoH, WoL,
        nullptr, nullptr, nullptr, nullptr, 1, 7500, 128, 256,
        b_out, (float*)d_out, nullptr, nullptr);
  }
}

// Round 3
// 827.504 us; speedup vs baseline: 1.8561x; 1.1208x over previous
//
#include <hip/hip_runtime.h>
#include <cstddef>
#include <cstdint>

#define CDIV(a,b) (((a)+(b)-1)/(b))
#define NEG_SLOPE 0.2f

typedef unsigned short u16;
typedef __attribute__((ext_vector_type(8))) short bf16x8;
typedef __attribute__((ext_vector_type(4))) float f32x4;

// ---------- bf16 helpers (explicit RNE, hi/lo split: v ~= hi + lo, ~17 mantissa bits) ----------
__device__ __forceinline__ u16 bf16_rne(float v){
  unsigned u = __float_as_uint(v);
  unsigned r = (u + 0x7FFFu + ((u >> 16) & 1u)) >> 16;
  return (u16)r;
}
__device__ __forceinline__ float bf16_to_f(u16 h){
  return __uint_as_float(((unsigned)h) << 16);
}
__device__ __forceinline__ void f2hilo(float v, u16& h, u16& l){
  h = bf16_rne(v);
  float r = v - bf16_to_f(h);
  l = bf16_rne(r);
}

// ---------- monotonic float<->uint encoding for atomicMax on floats ----------
__device__ __forceinline__ unsigned enc_f(float x){
  unsigned u = __float_as_uint(x);
  return (u & 0x80000000u) ? ~u : (u | 0x80000000u);
}
__device__ __forceinline__ float dec_f(unsigned k){
  unsigned u = (k & 0x80000000u) ? (k & 0x7FFFFFFFu) : ~k;
  return __uint_as_float(u);
}

__device__ __forceinline__ float sigmf(float x){ return 1.f / (1.f + expf(-x)); }

// ---------- async global->LDS, 16B per lane ----------
__device__ __forceinline__ void gload16(const void* g, void* l){
  __builtin_amdgcn_global_load_lds((const __attribute__((address_space(1))) void*)g,
                                   (__attribute__((address_space(3))) void*)l, 16, 0, 0);
}

// =====================================================================================
// Fused hi/lo MFMA GEMM: C[M,N] = sum_pairs (A_hi+A_lo)(B_hi+B_lo)^T, dropping lo*lo.
// Per k0 (BK=64): stage Ah+Al in LDS (XOR-swizzled via pre-swizzled global src, m173),
// then per kb: read Ah/Al frags from LDS, Bh/Bl frags DIRECT FROM GLOBAL (B panels are
// <=2MB weights -> L2-resident), issue 48 MFMA (3 phase-products x 16). 96 MFMA per
// 2-barrier window. B stored transposed [N][K] bf16. N%128==0, K%64==0, M arbitrary.
// Epilogue modes: (a) f32 C (+bias), (b) hi/lo bf16 out, (c) fused LSTM (gate-interleaved
// B layout: within each 64-col wave tile, cols = gate*16+ch16 -> a lane's 4 n-frags are
// i,f,g,o of ONE channel; computes c/h in-register, writes c f32 + h hi/lo).
// =====================================================================================
__global__ __launch_bounds__(256, 2) void mfma_gemm(
    const u16* __restrict__ Ah0, const u16* __restrict__ Al0,
    const u16* __restrict__ Bh0, const u16* __restrict__ Bl0,
    const u16* __restrict__ Ah1, const u16* __restrict__ Al1,
    const u16* __restrict__ Bh1, const u16* __restrict__ Bl1,
    int npairs, int M, int N, int K,
    const float* __restrict__ bias, float* __restrict__ Cf,
    u16* __restrict__ outHi, u16* __restrict__ outLo,
    const float* __restrict__ cIn, float* __restrict__ cOut,
    u16* __restrict__ hH, u16* __restrict__ hL, int lstm_first)
{
  __shared__ u16 smem[2 * 8192];  // Ah tile @0, Al tile @8192 (each 128x64 bf16 = 16KB)
  const int tid = threadIdx.x;
  const int lane = tid & 63, wv = tid >> 6;
  const int l15 = lane & 15, lq = lane >> 4;
  const int wr = wv >> 1, wc = wv & 1;
  const int bm = blockIdx.y * 128, bn = blockIdx.x * 128;
  const int rmA = M - bm;  // >= 1

  f32x4 acc[4][4];
  #pragma unroll
  for (int m = 0; m < 4; m++)
    #pragma unroll
    for (int n = 0; n < 4; n++) acc[m][n] = (f32x4){0.f, 0.f, 0.f, 0.f};

  // staging geometry: chunk c = i*256+tid covers LDS bytes c*16; row=c>>3, phys slot c&7,
  // logical slot s = (c&7) ^ (row&7)  (inverse-swizzled global source; LDS dest linear)
  int srow[4], sslot[4], ldso[4];
  #pragma unroll
  for (int i = 0; i < 4; i++){
    int c = i * 256 + tid;
    srow[i]  = c >> 3;
    sslot[i] = (c & 7) ^ (srow[i] & 7);
    ldso[i]  = (i * 256 + (tid & 192)) * 8;  // wave-uniform base, u16 units
  }

  #pragma unroll 1
  for (int q = 0; q < npairs; q++){
    const u16* Ah = q ? Ah1 : Ah0;  const u16* Al = q ? Al1 : Al0;
    const u16* Bh = q ? Bh1 : Bh0;  const u16* Bl = q ? Bl1 : Bl0;
    #pragma unroll 1
    for (int k0 = 0; k0 < K; k0 += 64){
      #pragma unroll
      for (int i = 0; i < 4; i++){
        int gr = srow[i] < rmA ? srow[i] : rmA - 1;  // clamp tail rows
        gload16(Ah + (size_t)(bm + gr) * K + k0 + sslot[i] * 8, smem + ldso[i]);
      }
      #pragma unroll
      for (int i = 0; i < 4; i++){
        int gr = srow[i] < rmA ? srow[i] : rmA - 1;
        gload16(Al + (size_t)(bm + gr) * K + k0 + sslot[i] * 8, smem + 8192 + ldso[i]);
      }
      __syncthreads();  // vmcnt(0) drain -> LDS valid
      #pragma unroll
      for (int kb = 0; kb < 8; kb += 4){
        bf16x8 ah[4], al[4], bh[4], bl[4];
        #pragma unroll
        for (int n = 0; n < 4; n++){
          int r = bn + wc * 64 + n * 16 + l15;
          const u16* pb = Bh + (size_t)r * K + k0 + (kb + lq) * 8;
          const u16* pl = Bl + (size_t)r * K + k0 + (kb + lq) * 8;
          bh[n] = *(const bf16x8*)pb;
          bl[n] = *(const bf16x8*)pl;
        }
        #pragma unroll
        for (int m = 0; m < 4; m++){
          int r = wr * 64 + m * 16 + l15;
          int s = (kb + lq) ^ (r & 7);
          ah[m] = *(const bf16x8*)(smem + r * 64 + s * 8);
          al[m] = *(const bf16x8*)(smem + 8192 + r * 64 + s * 8);
        }
        #pragma unroll
        for (int m = 0; m < 4; m++)
          #pragma unroll
          for (int n = 0; n < 4; n++){
            acc[m][n] = __builtin_amdgcn_mfma_f32_16x16x32_bf16(ah[m], bh[n], acc[m][n], 0, 0, 0);
            acc[m][n] = __builtin_amdgcn_mfma_f32_16x16x32_bf16(al[m], bh[n], acc[m][n], 0, 0, 0);
            acc[m][n] = __builtin_amdgcn_mfma_f32_16x16x32_bf16(ah[m], bl[n], acc[m][n], 0, 0, 0);
          }
      }
      __syncthreads();
    }
  }

  // epilogue: C/D layout col=lane&15, row=(lane>>4)*4+j (m89/m91-verified)
  const int rb = bm + wr * 64 + lq * 4;
  if (cOut){
    // LSTM mode: lane owns channel ch; n-frag index == gate (i,f,g,o)
    const int ch = (bn >> 2) + wc * 16 + l15;
    #pragma unroll
    for (int m = 0; m < 4; m++){
      #pragma unroll
      for (int j = 0; j < 4; j++){
        int row = rb + m * 16 + j;
        if (row >= M) continue;
        float i_ = acc[m][0][j], f_ = acc[m][1][j], g_ = acc[m][2][j], o_ = acc[m][3][j];
        float si = sigmf(i_), tg = tanhf(g_), so = sigmf(o_);
        size_t off = (size_t)row * 256 + ch;
        float cn = lstm_first ? si * tg : sigmf(f_) * cIn[off] + si * tg;
        float hn = so * tanhf(cn);
        cOut[off] = cn;
        u16 hh, hl; f2hilo(hn, hh, hl);
        hH[off] = hh; hL[off] = hl;
      }
    }
  } else {
    const int cb = bn + wc * 64 + l15;
    #pragma unroll
    for (int n = 0; n < 4; n++){
      int col = cb + n * 16;
      float bv = bias ? bias[col] : 0.f;
      #pragma unroll
      for (int m = 0; m < 4; m++){
        #pragma unroll
        for (int j = 0; j < 4; j++){
          int row = rb + m * 16 + j;
          if (row >= M) continue;
          float v = acc[m][n][j] + bv;
          size_t off = (size_t)row * N + col;
          if (Cf) Cf[off] = v;
          if (outHi){
            u16 hh, hl; f2hilo(v, hh, hl);
            outHi[off] = hh; outLo[off] = hl;
          }
        }
      }
    }
  }
}

// ---------- feats f32 -> hi/lo bf16, 4 elems/thread ----------
__global__ __launch_bounds__(256) void cvt_feats(const float* __restrict__ in,
    u16* __restrict__ hi, u16* __restrict__ lo, int n4){
  int i = blockIdx.x * 256 + threadIdx.x;
  if (i >= n4) return;
  float4 v = *(const float4*)(in + (size_t)i * 4);
  ushort4 h4, l4;
  f2hilo(v.x, h4.x, l4.x); f2hilo(v.y, h4.y, l4.y);
  f2hilo(v.z, h4.z, l4.z); f2hilo(v.w, h4.w, l4.w);
  *(ushort4*)(hi + (size_t)i * 4) = h4;
  *(ushort4*)(lo + (size_t)i * 4) = l4;
}

// ---------- one-shot weight prep: transpose/permute + hi/lo bf16 [N][K] ----------
// W_ih/W_hh rows are PERMUTED to gate-interleaved layout: orig row (gate*256+ch)
// -> n' = (ch>>4)*64 + gate*16 + (ch&15), so the GEMM epilogue can fuse LSTM.
__global__ __launch_bounds__(256) void prep_w(const float* __restrict__ Win,
    const float* __restrict__ Wsrc, const float* __restrict__ Wih,
    const float* __restrict__ Whh, const float* __restrict__ Wout,
    u16* WinH, u16* WinL, u16* WsH, u16* WsL,
    u16* IhH, u16* IhL, u16* HhH, u16* HhL, u16* WoH, u16* WoL){
  int idx = blockIdx.x * 256 + threadIdx.x;
  float v; u16 *ph, *pl; int off;
  if (idx < 32768){                       // WinT [256][128] <- Win[128][256]
    int n = idx >> 7, k = idx & 127;
    v = Win[k * 256 + n]; ph = WinH; pl = WinL; off = idx;
  } else if (idx < 229376){               // WsrcT [3][256][256] <- Wsrc (transposed)
    int t = idx - 32768; int hop = t >> 16, r = t & 65535, n = r >> 8, k = r & 255;
    v = Wsrc[hop * 65536 + k * 256 + n]; ph = WsH; pl = WsL; off = t;
  } else if (idx < 1015808){              // W_ih [3][1024][256], gate-interleaved rows
    int t = idx - 229376;
    int hop = t >> 18, r = (t >> 8) & 1023, k = t & 255;
    int gate = r >> 8, ch = r & 255;
    int np = ((ch >> 4) << 6) + (gate << 4) + (ch & 15);
    v = Wih[t]; ph = IhH; pl = IhL; off = hop * 262144 + np * 256 + k;
  } else if (idx < 1802240){              // W_hh, same permutation
    int t = idx - 1015808;
    int hop = t >> 18, r = (t >> 8) & 1023, k = t & 255;
    int gate = r >> 8, ch = r & 255;
    int np = ((ch >> 4) << 6) + (gate << 4) + (ch & 15);
    v = Whh[t]; ph = HhH; pl = HhL; off = hop * 262144 + np * 256 + k;
  } else if (idx < 1835008){              // WoutT [128][256] <- Wout[256][128]
    int t = idx - 1802240; int n = t >> 8, k = t & 255;
    v = Wout[k * 128 + n]; ph = WoH; pl = WoL; off = t;
  } else return;
  u16 hh, hl; f2hilo(v, hh, hl);
  ph[off] = hh; pl[off] = hl;
}

// ---------- w_s[hop] = Wsrc[hop]@a_s, w_d[hop] = Wdst[hop]@a_d (row dots, f32) ----------
__global__ __launch_bounds__(256) void prep_wvec(const float* __restrict__ Wsrc,
    const float* __restrict__ Wdst, const float* __restrict__ as_,
    const float* __restrict__ ad_, float* __restrict__ wsv, float* __restrict__ wdv){
  int wid = blockIdx.x * 4 + (threadIdx.x >> 6), lane = threadIdx.x & 63;
  if (wid >= 6 * 256) return;
  int vec = wid >> 8, i = wid & 255;
  int hop = vec >> 1; bool isd = vec & 1;
  const float* Wrow = (isd ? Wdst : Wsrc) + (size_t)hop * 65536 + (size_t)i * 256;
  const float* a = (isd ? ad_ : as_) + hop * 256;
  float4 w4 = *(const float4*)(Wrow + lane * 4);
  float4 a4 = *(const float4*)(a + lane * 4);
  float v = w4.x * a4.x + w4.y * a4.y + w4.z * a4.z + w4.w * a4.w;
  #pragma unroll
  for (int off = 32; off; off >>= 1) v += __shfl_down(v, off);
  if (!lane) (isd ? wdv : wsv)[hop * 256 + i] = v;
}

// ---------- alpha_s[m]=x[m]@w_s, alpha_d[m]=x[m]@w_d from hi/lo x; one wave/row ----------
__global__ __launch_bounds__(256) void alpha_mv(const u16* __restrict__ xh,
    const u16* __restrict__ xl, const float* __restrict__ wsv, const float* __restrict__ wdv,
    float* __restrict__ as_out, float* __restrict__ ad_out, int ns, int nd){
  int wid = blockIdx.x * 4 + (threadIdx.x >> 6), lane = threadIdx.x & 63;
  if (wid >= ns + nd) return;
  bool isd = wid >= ns;
  int row = isd ? wid - ns : wid;
  ushort4 vh = *(const ushort4*)(xh + (size_t)row * 256 + lane * 4);
  ushort4 vl = *(const ushort4*)(xl + (size_t)row * 256 + lane * 4);
  const float* wv = isd ? wdv : wsv;
  float4 w4 = *(const float4*)(wv + lane * 4);
  float v = (bf16_to_f(vh.x) + bf16_to_f(vl.x)) * w4.x
          + (bf16_to_f(vh.y) + bf16_to_f(vl.y)) * w4.y
          + (bf16_to_f(vh.z) + bf16_to_f(vl.z)) * w4.z
          + (bf16_to_f(vh.w) + bf16_to_f(vl.w)) * w4.w;
  #pragma unroll
  for (int off = 32; off; off >>= 1) v += __shfl_down(v, off);
  if (!lane) (isd ? ad_out : as_out)[row] = v;
}

// ---------- edges + self-loops: leaky-relu alpha, segment max (encoded), degree ----------
__global__ __launch_bounds__(256) void edge_a(const int* __restrict__ src,
    const int* __restrict__ dst, const float* __restrict__ as_, const float* __restrict__ ad_,
    float* __restrict__ alpha_e, float* __restrict__ alpha_self,
    unsigned* __restrict__ amax, int* __restrict__ cnt, int E, int nd){
  int i = blockIdx.x * 256 + threadIdx.x;
  if (i < E){
    int s = src[i], d = dst[i];
    float al = as_[s] + ad_[d];
    al = al > 0.f ? al : NEG_SLOPE * al;
    alpha_e[i] = al;
    atomicMax(&amax[d], enc_f(al));
    atomicAdd(&cnt[d], 1);
  } else if (i < E + nd){
    int j = i - E;
    float al = as_[j] + ad_[j];
    al = al > 0.f ? al : NEG_SLOPE * al;
    alpha_self[j] = al;
    atomicMax(&amax[j], enc_f(al));
  }
}

// ---------- parallel scan: per-block totals -> serial scan of totals -> finalize ----------
__global__ __launch_bounds__(256) void scan_part(const int* __restrict__ cnt,
    int* __restrict__ part, int n){
  __shared__ int ws_[4];
  int lane = threadIdx.x & 63, wv = threadIdx.x >> 6;
  int i = blockIdx.x * 256 + threadIdx.x;
  int v = (i < n) ? cnt[i] : 0;
  #pragma unroll
  for (int off = 32; off; off >>= 1) v += __shfl_down(v, off);
  if (!lane) ws_[wv] = v;
  __syncthreads();
  if (!threadIdx.x) part[blockIdx.x] = ws_[0] + ws_[1] + ws_[2] + ws_[3];
}
__global__ void scan_tot(int* __restrict__ part, int nb){
  if (threadIdx.x == 0){
    int s = 0;
    for (int b = 0; b < nb; b++){ int t = part[b]; part[b] = s; s += t; }
  }
}
__global__ __launch_bounds__(256) void scan_fin(const int* __restrict__ cnt,
    const int* __restrict__ part, int* __restrict__ base, int* __restrict__ cursor, int n){
  __shared__ int wtot[4];
  int lane = threadIdx.x & 63, wv = threadIdx.x >> 6;
  int i = blockIdx.x * 256 + threadIdx.x;
  int v = (i < n) ? cnt[i] : 0;
  int incl = v;
  #pragma unroll
  for (int off = 1; off < 64; off <<= 1){
    int t = __shfl_up(incl, off);
    if (lane >= off) incl += t;
  }
  if (lane == 63) wtot[wv] = incl;
  __syncthreads();
  int woff = part[blockIdx.x];
  for (int w = 0; w < wv; w++) woff += wtot[w];
  int excl = woff + incl - v;
  if (i < n){ base[i] = excl; cursor[i] = excl; }
}

// ---------- e=exp(alpha-amax), CSR fill ----------
__global__ __launch_bounds__(256) void edge_b(const int* __restrict__ src,
    const int* __restrict__ dst, const float* __restrict__ alpha_e,
    const unsigned* __restrict__ amax, int* __restrict__ cursor,
    int* __restrict__ csr_src, float* __restrict__ csr_e, int E){
  int e = blockIdx.x * 256 + threadIdx.x;
  if (e >= E) return;
  int d = dst[e];
  float ev = expf(alpha_e[e] - dec_f(amax[d]));
  int pos = atomicAdd(&cursor[d], 1);
  csr_src[pos] = src[e];
  csr_e[pos] = ev;
}

// ---------- gather + normalize + bias + tanh -> xb hi/lo bf16; one wave/dst ----------
__global__ __launch_bounds__(256) void gather_xb(const float* __restrict__ xs,
    const int* __restrict__ base, const int* __restrict__ cnt,
    const int* __restrict__ csr_src, const float* __restrict__ csr_e,
    const float* __restrict__ alpha_self, const unsigned* __restrict__ amax,
    const float* __restrict__ gb, u16* __restrict__ xbH, u16* __restrict__ xbL, int n){
  int wv = threadIdx.x >> 6, lane = threadIdx.x & 63;
  int j = blockIdx.x * 4 + wv;
  if (j >= n) return;
  int b0 = base[j], cn = cnt[j];
  float ax = 0.f, ay = 0.f, az = 0.f, aw = 0.f, ds = 0.f;
  for (int k = 0; k < cn; k++){
    int s = csr_src[b0 + k];
    float ev = csr_e[b0 + k];
    float4 x4 = *(const float4*)(xs + (size_t)s * 256 + lane * 4);
    ax += ev * x4.x; ay += ev * x4.y; az += ev * x4.z; aw += ev * x4.w; ds += ev;
  }
  float es = expf(alpha_self[j] - dec_f(amax[j]));
  float4 x4 = *(const float4*)(xs + (size_t)j * 256 + lane * 4);
  ax += es * x4.x; ay += es * x4.y; az += es * x4.z; aw += es * x4.w; ds += es;
  float inv = 1.f / ds;
  float4 g4 = *(const float4*)(gb + lane * 4);
  float o0 = tanhf(ax * inv + g4.x), o1 = tanhf(ay * inv + g4.y);
  float o2 = tanhf(az * inv + g4.z), o3 = tanhf(aw * inv + g4.w);
  ushort4 h4, l4;
  f2hilo(o0, h4.x, l4.x); f2hilo(o1, h4.y, l4.y);
  f2hilo(o2, h4.z, l4.z); f2hilo(o3, h4.w, l4.w);
  *(ushort4*)(xbH + (size_t)j * 256 + lane * 4) = h4;
  *(ushort4*)(xbL + (size_t)j * 256 + lane * 4) = l4;
}

extern "C" void kernel_launch(void* const* d_in, const int* in_sizes, int n_in,
                              void* d_out, int out_size, void* d_ws, size_t ws_size,
                              hipStream_t stream){
  const float* feats   = (const float*)d_in[0];
  const float* Win     = (const float*)d_in[1];
  const float* b_in    = (const float*)d_in[2];
  const float* Wsrc    = (const float*)d_in[3];
  const float* Wdst    = (const float*)d_in[4];
  const float* att_src = (const float*)d_in[5];
  const float* att_dst = (const float*)d_in[6];
  const float* gat_b   = (const float*)d_in[7];
  const float* W_ih    = (const float*)d_in[8];
  const float* W_hh    = (const float*)d_in[9];
  const float* Wout    = (const float*)d_in[10];
  const float* b_out   = (const float*)d_in[11];
  const int* srcs[3] = {(const int*)d_in[12], (const int*)d_in[14], (const int*)d_in[16]};
  const int* dsts[3] = {(const int*)d_in[13], (const int*)d_in[15], (const int*)d_in[17]};
  (void)in_sizes; (void)n_in; (void)out_size; (void)ws_size;

  const int ns_a[3] = {60000, 30000, 15000};
  const int nd_a[3] = {30000, 15000, 7500};
  const int E_a[3]  = {480000, 240000, 120000};

  // ---- workspace layout (~229 MiB), aliasing lifetime-checked ----
  char* w = (char*)d_ws;
  float* xs    = (float*)(w + 0);                 // [60000][256] f32
  u16* featsH  = (u16*)(w + 0);                   // alias: dead before xs written
  u16* featsL  = (u16*)(w + 30720000);
  u16* x0H     = (u16*)(w + 61440000);            // hop-0 x hi/lo
  u16* x0L     = (u16*)(w + 92160000);
  float* c     = (float*)(w + 61440000);          // alias x0H: first write (hop0 epi) after x0 dead
  u16* hAH     = (u16*)(w + 122880000);           // h ping-pong set A
  u16* hAL     = (u16*)(w + 138240000);
  u16* hBH     = (u16*)(w + 153600000);           // set B
  u16* hBL     = (u16*)(w + 168960000);
  u16* xbH     = (u16*)(w + 184320000);
  u16* xbL     = (u16*)(w + 199680000);
  u16* WinH = (u16*)(w + 215040000);  u16* WinL = WinH + 32768;
  u16* WsH  = WinL + 32768;           u16* WsL  = WsH + 196608;
  u16* IhH  = WsL + 196608;           u16* IhL  = IhH + 786432;
  u16* HhH  = IhL + 786432;           u16* HhL  = HhH + 786432;
  u16* WoH  = HhL + 786432;           u16* WoL  = WoH + 32768;
  float* wsv = (float*)(WoL + 32768); float* wdv = wsv + 768;
  float* alpha_s    = wdv + 768;
  float* alpha_d    = alpha_s + 60000;
  float* alpha_e    = alpha_d + 30000;
  float* alpha_self = alpha_e + 480000;
  unsigned* amax    = (unsigned*)(alpha_self + 30000);
  int* cnt          = (int*)(amax + 30000);
  int* base         = cnt + 30000;
  int* cursor       = base + 30000;
  int* part         = cursor + 30000;             // scan partials (<=128)
  int* csr_src      = part + 256;
  float* csr_e      = (float*)(csr_src + 480000);

  // ---- one-time prep (inputs only) ----
  prep_w<<<7168, 256, 0, stream>>>(Win, Wsrc, W_ih, W_hh, Wout,
      WinH, WinL, WsH, WsL, IhH, IhL, HhH, HhL, WoH, WoL);
  prep_wvec<<<384, 256, 0, stream>>>(Wsrc, Wdst, att_src, att_dst, wsv, wdv);
  cvt_feats<<<7500, 256, 0, stream>>>(feats, featsH, featsL, 1920000);

  // ---- input projection: x0(hi/lo) = feats @ Win + b_in ----
  {
    dim3 g(2, CDIV(60000, 128));
    mfma_gemm<<<g, 256, 0, stream>>>(featsH, featsL, WinH, WinL,
        nullptr, nullptr, nullptr, nullptr, 1, 60000, 256, 128,
        b_in, nullptr, x0H, x0L, nullptr, nullptr, nullptr, nullptr, 0);
  }

  const u16* xHp = x0H; const u16* xLp = x0L;
  u16* hCurH = hAH; u16* hCurL = hAL;   // h produced by previous hop (input to pair1)
  u16* hNewH = hAH; u16* hNewL = hAL;   // h written this hop
  for (int hop = 0; hop < 3; hop++){
    const int ns = ns_a[hop], nd = nd_a[hop], E = E_a[hop];
    const int nb = CDIV(nd, 256);
    hipMemsetAsync(amax, 0, (size_t)(30000 + nd) * 4, stream);  // amax[30000] + cnt[0..nd)

    // xs = x @ Wsrc[hop]   (f32 out, feeds gather)
    {
      dim3 g(2, CDIV(ns, 128));
      mfma_gemm<<<g, 256, 0, stream>>>(xHp, xLp, WsH + (size_t)hop * 65536, WsL + (size_t)hop * 65536,
          nullptr, nullptr, nullptr, nullptr, 1, ns, 256, 256,
          nullptr, xs, nullptr, nullptr, nullptr, nullptr, nullptr, nullptr, 0);
    }
    alpha_mv<<<CDIV(ns + nd, 4), 256, 0, stream>>>(xHp, xLp, wsv + hop * 256, wdv + hop * 256,
        alpha_s, alpha_d, ns, nd);
    edge_a<<<CDIV(E + nd, 256), 256, 0, stream>>>(srcs[hop], dsts[hop], alpha_s, alpha_d,
        alpha_e, alpha_self, amax, cnt, E, nd);
    scan_part<<<nb, 256, 0, stream>>>(cnt, part, nd);
    scan_tot<<<1, 64, 0, stream>>>(part, nb);
    scan_fin<<<nb, 256, 0, stream>>>(cnt, part, base, cursor, nd);
    edge_b<<<CDIV(E, 256), 256, 0, stream>>>(srcs[hop], dsts[hop], alpha_e, amax,
        cursor, csr_src, csr_e, E);
    gather_xb<<<CDIV(nd, 4), 256, 0, stream>>>(xs, base, cnt, csr_src, csr_e,
        alpha_self, amax, gat_b + hop * 256, xbH, xbL, nd);

    // gates GEMM with fused LSTM epilogue; h double-buffered (epilogue write vs pair1 read)
    hNewH = (hop == 0) ? hAH : (hCurH == hAH ? hBH : hAH);
    hNewL = (hop == 0) ? hAL : (hCurL == hAL ? hBL : hAL);
    {
      dim3 g(8, CDIV(nd, 128));
      mfma_gemm<<<g, 256, 0, stream>>>(xbH, xbL, IhH + (size_t)hop * 262144, IhL + (size_t)hop * 262144,
          hCurH, hCurL, HhH + (size_t)hop * 262144, HhL + (size_t)hop * 262144,
          hop ? 2 : 1, nd, 1024, 256,
          nullptr, nullptr, nullptr, nullptr,
          c, c, hNewH, hNewL, hop == 0 ? 1 : 0);
    }
    hCurH = hNewH; hCurL = hNewL;
    xHp = hNewH; xLp = hNewL;
  }

  // ---- output projection: d_out = h @ Wout + b_out ----
  {
    dim3 g(1, CDIV(7500, 128));
    mfma_gemm<<<g, 256, 0, stream>>>(hCurH, hCurL, WoH, WoL,
        nullptr, nullptr, nullptr, nullptr, 1, 7500, 128, 256,
        b_out, (float*)d_out, nullptr, nullptr, nullptr, nullptr, nullptr, nullptr, 0);
  }
}

// Round 4
// 693.948 us; speedup vs baseline: 2.2133x; 1.1925x over previous
//
#include <hip/hip_runtime.h>
#include <cstddef>
#include <cstdint>

#define CDIV(a,b) (((a)+(b)-1)/(b))
#define NEG_SLOPE 0.2f

typedef unsigned short u16;
typedef __attribute__((ext_vector_type(8))) short bf16x8;
typedef __attribute__((ext_vector_type(4))) float f32x4;

// ---------- bf16 helpers (explicit RNE, hi/lo split: v ~= hi + lo, ~17 mantissa bits) ----------
__device__ __forceinline__ u16 bf16_rne(float v){
  unsigned u = __float_as_uint(v);
  unsigned r = (u + 0x7FFFu + ((u >> 16) & 1u)) >> 16;
  return (u16)r;
}
__device__ __forceinline__ float bf16_to_f(u16 h){
  return __uint_as_float(((unsigned)h) << 16);
}
__device__ __forceinline__ void f2hilo(float v, u16& h, u16& l){
  h = bf16_rne(v);
  float r = v - bf16_to_f(h);
  l = bf16_rne(r);
}

// ---------- monotonic float<->uint encoding for atomicMax on floats ----------
__device__ __forceinline__ unsigned enc_f(float x){
  unsigned u = __float_as_uint(x);
  return (u & 0x80000000u) ? ~u : (u | 0x80000000u);
}
__device__ __forceinline__ float dec_f(unsigned k){
  unsigned u = (k & 0x80000000u) ? (k & 0x7FFFFFFFu) : ~k;
  return __uint_as_float(u);
}

__device__ __forceinline__ float sigmf(float x){ return 1.f / (1.f + expf(-x)); }

// ---------- async global->LDS, 16B per lane ----------
__device__ __forceinline__ void gload16(const void* g, void* l){
  __builtin_amdgcn_global_load_lds((const __attribute__((address_space(1))) void*)g,
                                   (__attribute__((address_space(3))) void*)l, 16, 0, 0);
}

// =====================================================================================
// Fused hi/lo MFMA GEMM: C[M,N] = sum_pairs (A_hi+A_lo)(B_hi+B_lo)^T, dropping lo*lo.
// Per k0 (BK=64): stage FOUR tiles in LDS (Ah,Al,Bh,Bl, each [128][64] bf16 = 16KB,
// 64KB total, XOR-swizzled via pre-swizzled global src, m173). Then per kb (2 of them):
// 16x ds_read_b128 frags + 48 MFMA -> 96 MFMA per 2-barrier window (3x round-2 density,
// all operands from LDS so the compiler pipelines with counted lgkmcnt — fixes the
// round-3 latency-bound regression from direct-global B frags).
// B stored transposed [N][K] bf16. N%128==0, K%64==0, M arbitrary.
// Epilogue modes: (a) f32 C (+bias), (b) hi/lo bf16 out, (c) fused LSTM (gate-interleaved
// B layout: lane's 4 n-frags are i,f,g,o of ONE channel; writes c f32 + h hi/lo).
// =====================================================================================
__global__ __launch_bounds__(256, 2) void mfma_gemm(
    const u16* __restrict__ Ah0, const u16* __restrict__ Al0,
    const u16* __restrict__ Bh0, const u16* __restrict__ Bl0,
    const u16* __restrict__ Ah1, const u16* __restrict__ Al1,
    const u16* __restrict__ Bh1, const u16* __restrict__ Bl1,
    int npairs, int M, int N, int K,
    const float* __restrict__ bias, float* __restrict__ Cf,
    u16* __restrict__ outHi, u16* __restrict__ outLo,
    const float* __restrict__ cIn, float* __restrict__ cOut,
    u16* __restrict__ hH, u16* __restrict__ hL, int lstm_first)
{
  __shared__ u16 smem[4 * 8192];  // Ah@0, Al@8192, Bh@16384, Bl@24576 (u16 units)
  const int tid = threadIdx.x;
  const int lane = tid & 63, wv = tid >> 6;
  const int l15 = lane & 15, lq = lane >> 4;
  const int wr = wv >> 1, wc = wv & 1;
  const int bm = blockIdx.y * 128, bn = blockIdx.x * 128;
  const int rmA = M - bm;  // >= 1

  f32x4 acc[4][4];
  #pragma unroll
  for (int m = 0; m < 4; m++)
    #pragma unroll
    for (int n = 0; n < 4; n++) acc[m][n] = (f32x4){0.f, 0.f, 0.f, 0.f};

  // staging geometry: chunk c = i*256+tid covers LDS bytes c*16; row=c>>3, phys slot c&7,
  // logical slot s = (c&7) ^ (row&7)  (inverse-swizzled global source; LDS dest linear)
  int srowA[4], srow[4], sslot[4], ldso[4];
  #pragma unroll
  for (int i = 0; i < 4; i++){
    int c = i * 256 + tid;
    srow[i]  = c >> 3;
    sslot[i] = (c & 7) ^ (srow[i] & 7);
    srowA[i] = srow[i] < rmA ? srow[i] : rmA - 1;  // clamp A tail rows
    ldso[i]  = (i * 256 + (tid & 192)) * 8;  // wave-uniform base, u16 units
  }

  #pragma unroll 1
  for (int q = 0; q < npairs; q++){
    const u16* Ah = q ? Ah1 : Ah0;  const u16* Al = q ? Al1 : Al0;
    const u16* Bh = q ? Bh1 : Bh0;  const u16* Bl = q ? Bl1 : Bl0;
    #pragma unroll 1
    for (int k0 = 0; k0 < K; k0 += 64){
      #pragma unroll
      for (int i = 0; i < 4; i++){
        size_t ao = (size_t)(bm + srowA[i]) * K + k0 + sslot[i] * 8;
        size_t bo = (size_t)(bn + srow[i])  * K + k0 + sslot[i] * 8;
        gload16(Ah + ao, smem + ldso[i]);
        gload16(Al + ao, smem + 8192 + ldso[i]);
        gload16(Bh + bo, smem + 16384 + ldso[i]);
        gload16(Bl + bo, smem + 24576 + ldso[i]);
      }
      __syncthreads();  // vmcnt(0) drain -> LDS valid
      #pragma unroll
      for (int kb = 0; kb < 8; kb += 4){
        bf16x8 ah[4], al[4], bh[4], bl[4];
        #pragma unroll
        for (int m = 0; m < 4; m++){
          int r = wr * 64 + m * 16 + l15;
          int s = (kb + lq) ^ (r & 7);
          ah[m] = *(const bf16x8*)(smem + r * 64 + s * 8);
          al[m] = *(const bf16x8*)(smem + 8192 + r * 64 + s * 8);
        }
        #pragma unroll
        for (int n = 0; n < 4; n++){
          int r = wc * 64 + n * 16 + l15;
          int s = (kb + lq) ^ (r & 7);
          bh[n] = *(const bf16x8*)(smem + 16384 + r * 64 + s * 8);
          bl[n] = *(const bf16x8*)(smem + 24576 + r * 64 + s * 8);
        }
        #pragma unroll
        for (int m = 0; m < 4; m++)
          #pragma unroll
          for (int n = 0; n < 4; n++){
            acc[m][n] = __builtin_amdgcn_mfma_f32_16x16x32_bf16(ah[m], bh[n], acc[m][n], 0, 0, 0);
            acc[m][n] = __builtin_amdgcn_mfma_f32_16x16x32_bf16(al[m], bh[n], acc[m][n], 0, 0, 0);
            acc[m][n] = __builtin_amdgcn_mfma_f32_16x16x32_bf16(ah[m], bl[n], acc[m][n], 0, 0, 0);
          }
      }
      __syncthreads();
    }
  }

  // epilogue: C/D layout col=lane&15, row=(lane>>4)*4+j (m89/m91-verified)
  const int rb = bm + wr * 64 + lq * 4;
  if (cOut){
    // LSTM mode: lane owns channel ch; n-frag index == gate (i,f,g,o)
    const int ch = (bn >> 2) + wc * 16 + l15;
    #pragma unroll
    for (int m = 0; m < 4; m++){
      #pragma unroll
      for (int j = 0; j < 4; j++){
        int row = rb + m * 16 + j;
        if (row >= M) continue;
        float i_ = acc[m][0][j], f_ = acc[m][1][j], g_ = acc[m][2][j], o_ = acc[m][3][j];
        float si = sigmf(i_), tg = tanhf(g_), so = sigmf(o_);
        size_t off = (size_t)row * 256 + ch;
        float cn = lstm_first ? si * tg : sigmf(f_) * cIn[off] + si * tg;
        float hn = so * tanhf(cn);
        cOut[off] = cn;
        u16 hh, hl; f2hilo(hn, hh, hl);
        hH[off] = hh; hL[off] = hl;
      }
    }
  } else {
    const int cb = bn + wc * 64 + l15;
    #pragma unroll
    for (int n = 0; n < 4; n++){
      int col = cb + n * 16;
      float bv = bias ? bias[col] : 0.f;
      #pragma unroll
      for (int m = 0; m < 4; m++){
        #pragma unroll
        for (int j = 0; j < 4; j++){
          int row = rb + m * 16 + j;
          if (row >= M) continue;
          float v = acc[m][n][j] + bv;
          size_t off = (size_t)row * N + col;
          if (Cf) Cf[off] = v;
          if (outHi){
            u16 hh, hl; f2hilo(v, hh, hl);
            outHi[off] = hh; outLo[off] = hl;
          }
        }
      }
    }
  }
}

// ---------- feats f32 -> hi/lo bf16, 4 elems/thread ----------
__global__ __launch_bounds__(256) void cvt_feats(const float* __restrict__ in,
    u16* __restrict__ hi, u16* __restrict__ lo, int n4){
  int i = blockIdx.x * 256 + threadIdx.x;
  if (i >= n4) return;
  float4 v = *(const float4*)(in + (size_t)i * 4);
  ushort4 h4, l4;
  f2hilo(v.x, h4.x, l4.x); f2hilo(v.y, h4.y, l4.y);
  f2hilo(v.z, h4.z, l4.z); f2hilo(v.w, h4.w, l4.w);
  *(ushort4*)(hi + (size_t)i * 4) = h4;
  *(ushort4*)(lo + (size_t)i * 4) = l4;
}

// ---------- one-shot weight prep: transpose/permute + hi/lo bf16 [N][K] ----------
// W_ih/W_hh rows are PERMUTED to gate-interleaved layout: orig row (gate*256+ch)
// -> n' = (ch>>4)*64 + gate*16 + (ch&15), so the GEMM epilogue can fuse LSTM.
__global__ __launch_bounds__(256) void prep_w(const float* __restrict__ Win,
    const float* __restrict__ Wsrc, const float* __restrict__ Wih,
    const float* __restrict__ Whh, const float* __restrict__ Wout,
    u16* WinH, u16* WinL, u16* WsH, u16* WsL,
    u16* IhH, u16* IhL, u16* HhH, u16* HhL, u16* WoH, u16* WoL){
  int idx = blockIdx.x * 256 + threadIdx.x;
  float v; u16 *ph, *pl; int off;
  if (idx < 32768){                       // WinT [256][128] <- Win[128][256]
    int n = idx >> 7, k = idx & 127;
    v = Win[k * 256 + n]; ph = WinH; pl = WinL; off = idx;
  } else if (idx < 229376){               // WsrcT [3][256][256] <- Wsrc (transposed)
    int t = idx - 32768; int hop = t >> 16, r = t & 65535, n = r >> 8, k = r & 255;
    v = Wsrc[hop * 65536 + k * 256 + n]; ph = WsH; pl = WsL; off = t;
  } else if (idx < 1015808){              // W_ih [3][1024][256], gate-interleaved rows
    int t = idx - 229376;
    int hop = t >> 18, r = (t >> 8) & 1023, k = t & 255;
    int gate = r >> 8, ch = r & 255;
    int np = ((ch >> 4) << 6) + (gate << 4) + (ch & 15);
    v = Wih[t]; ph = IhH; pl = IhL; off = hop * 262144 + np * 256 + k;
  } else if (idx < 1802240){              // W_hh, same permutation
    int t = idx - 1015808;
    int hop = t >> 18, r = (t >> 8) & 1023, k = t & 255;
    int gate = r >> 8, ch = r & 255;
    int np = ((ch >> 4) << 6) + (gate << 4) + (ch & 15);
    v = Whh[t]; ph = HhH; pl = HhL; off = hop * 262144 + np * 256 + k;
  } else if (idx < 1835008){              // WoutT [128][256] <- Wout[256][128]
    int t = idx - 1802240; int n = t >> 8, k = t & 255;
    v = Wout[k * 128 + n]; ph = WoH; pl = WoL; off = t;
  } else return;
  u16 hh, hl; f2hilo(v, hh, hl);
  ph[off] = hh; pl[off] = hl;
}

// ---------- w_s[hop] = Wsrc[hop]@a_s, w_d[hop] = Wdst[hop]@a_d (row dots, f32) ----------
__global__ __launch_bounds__(256) void prep_wvec(const float* __restrict__ Wsrc,
    const float* __restrict__ Wdst, const float* __restrict__ as_,
    const float* __restrict__ ad_, float* __restrict__ wsv, float* __restrict__ wdv){
  int wid = blockIdx.x * 4 + (threadIdx.x >> 6), lane = threadIdx.x & 63;
  if (wid >= 6 * 256) return;
  int vec = wid >> 8, i = wid & 255;
  int hop = vec >> 1; bool isd = vec & 1;
  const float* Wrow = (isd ? Wdst : Wsrc) + (size_t)hop * 65536 + (size_t)i * 256;
  const float* a = (isd ? ad_ : as_) + hop * 256;
  float4 w4 = *(const float4*)(Wrow + lane * 4);
  float4 a4 = *(const float4*)(a + lane * 4);
  float v = w4.x * a4.x + w4.y * a4.y + w4.z * a4.z + w4.w * a4.w;
  #pragma unroll
  for (int off = 32; off; off >>= 1) v += __shfl_down(v, off);
  if (!lane) (isd ? wdv : wsv)[hop * 256 + i] = v;
}

// ---------- alpha_s[m]=x[m]@w_s, alpha_d[m]=x[m]@w_d from hi/lo x; one wave/row ----------
__global__ __launch_bounds__(256) void alpha_mv(const u16* __restrict__ xh,
    const u16* __restrict__ xl, const float* __restrict__ wsv, const float* __restrict__ wdv,
    float* __restrict__ as_out, float* __restrict__ ad_out, int ns, int nd){
  int wid = blockIdx.x * 4 + (threadIdx.x >> 6), lane = threadIdx.x & 63;
  if (wid >= ns + nd) return;
  bool isd = wid >= ns;
  int row = isd ? wid - ns : wid;
  ushort4 vh = *(const ushort4*)(xh + (size_t)row * 256 + lane * 4);
  ushort4 vl = *(const ushort4*)(xl + (size_t)row * 256 + lane * 4);
  const float* wv = isd ? wdv : wsv;
  float4 w4 = *(const float4*)(wv + lane * 4);
  float v = (bf16_to_f(vh.x) + bf16_to_f(vl.x)) * w4.x
          + (bf16_to_f(vh.y) + bf16_to_f(vl.y)) * w4.y
          + (bf16_to_f(vh.z) + bf16_to_f(vl.z)) * w4.z
          + (bf16_to_f(vh.w) + bf16_to_f(vl.w)) * w4.w;
  #pragma unroll
  for (int off = 32; off; off >>= 1) v += __shfl_down(v, off);
  if (!lane) (isd ? ad_out : as_out)[row] = v;
}

// ---------- edges + self-loops: leaky-relu alpha, segment max (encoded), degree ----------
__global__ __launch_bounds__(256) void edge_a(const int* __restrict__ src,
    const int* __restrict__ dst, const float* __restrict__ as_, const float* __restrict__ ad_,
    float* __restrict__ alpha_e, float* __restrict__ alpha_self,
    unsigned* __restrict__ amax, int* __restrict__ cnt, int E, int nd){
  int i = blockIdx.x * 256 + threadIdx.x;
  if (i < E){
    int s = src[i], d = dst[i];
    float al = as_[s] + ad_[d];
    al = al > 0.f ? al : NEG_SLOPE * al;
    alpha_e[i] = al;
    atomicMax(&amax[d], enc_f(al));
    atomicAdd(&cnt[d], 1);
  } else if (i < E + nd){
    int j = i - E;
    float al = as_[j] + ad_[j];
    al = al > 0.f ? al : NEG_SLOPE * al;
    alpha_self[j] = al;
    atomicMax(&amax[j], enc_f(al));
  }
}

// ---------- parallel scan: per-block totals -> serial scan of totals -> finalize ----------
__global__ __launch_bounds__(256) void scan_part(const int* __restrict__ cnt,
    int* __restrict__ part, int n){
  __shared__ int ws_[4];
  int lane = threadIdx.x & 63, wv = threadIdx.x >> 6;
  int i = blockIdx.x * 256 + threadIdx.x;
  int v = (i < n) ? cnt[i] : 0;
  #pragma unroll
  for (int off = 32; off; off >>= 1) v += __shfl_down(v, off);
  if (!lane) ws_[wv] = v;
  __syncthreads();
  if (!threadIdx.x) part[blockIdx.x] = ws_[0] + ws_[1] + ws_[2] + ws_[3];
}
__global__ void scan_tot(int* __restrict__ part, int nb){
  if (threadIdx.x == 0){
    int s = 0;
    for (int b = 0; b < nb; b++){ int t = part[b]; part[b] = s; s += t; }
  }
}
__global__ __launch_bounds__(256) void scan_fin(const int* __restrict__ cnt,
    const int* __restrict__ part, int* __restrict__ base, int* __restrict__ cursor, int n){
  __shared__ int wtot[4];
  int lane = threadIdx.x & 63, wv = threadIdx.x >> 6;
  int i = blockIdx.x * 256 + threadIdx.x;
  int v = (i < n) ? cnt[i] : 0;
  int incl = v;
  #pragma unroll
  for (int off = 1; off < 64; off <<= 1){
    int t = __shfl_up(incl, off);
    if (lane >= off) incl += t;
  }
  if (lane == 63) wtot[wv] = incl;
  __syncthreads();
  int woff = part[blockIdx.x];
  for (int w = 0; w < wv; w++) woff += wtot[w];
  int excl = woff + incl - v;
  if (i < n){ base[i] = excl; cursor[i] = excl; }
}

// ---------- e=exp(alpha-amax), CSR fill ----------
__global__ __launch_bounds__(256) void edge_b(const int* __restrict__ src,
    const int* __restrict__ dst, const float* __restrict__ alpha_e,
    const unsigned* __restrict__ amax, int* __restrict__ cursor,
    int* __restrict__ csr_src, float* __restrict__ csr_e, int E){
  int e = blockIdx.x * 256 + threadIdx.x;
  if (e >= E) return;
  int d = dst[e];
  float ev = expf(alpha_e[e] - dec_f(amax[d]));
  int pos = atomicAdd(&cursor[d], 1);
  csr_src[pos] = src[e];
  csr_e[pos] = ev;
}

// ---------- gather + normalize + bias + tanh -> xb hi/lo bf16; one wave/dst ----------
__global__ __launch_bounds__(256) void gather_xb(const float* __restrict__ xs,
    const int* __restrict__ base, const int* __restrict__ cnt,
    const int* __restrict__ csr_src, const float* __restrict__ csr_e,
    const float* __restrict__ alpha_self, const unsigned* __restrict__ amax,
    const float* __restrict__ gb, u16* __restrict__ xbH, u16* __restrict__ xbL, int n){
  int wv = threadIdx.x >> 6, lane = threadIdx.x & 63;
  int j = blockIdx.x * 4 + wv;
  if (j >= n) return;
  int b0 = base[j], cn = cnt[j];
  float ax = 0.f, ay = 0.f, az = 0.f, aw = 0.f, ds = 0.f;
  for (int k = 0; k < cn; k++){
    int s = csr_src[b0 + k];
    float ev = csr_e[b0 + k];
    float4 x4 = *(const float4*)(xs + (size_t)s * 256 + lane * 4);
    ax += ev * x4.x; ay += ev * x4.y; az += ev * x4.z; aw += ev * x4.w; ds += ev;
  }
  float es = expf(alpha_self[j] - dec_f(amax[j]));
  float4 x4 = *(const float4*)(xs + (size_t)j * 256 + lane * 4);
  ax += es * x4.x; ay += es * x4.y; az += es * x4.z; aw += es * x4.w; ds += es;
  float inv = 1.f / ds;
  float4 g4 = *(const float4*)(gb + lane * 4);
  float o0 = tanhf(ax * inv + g4.x), o1 = tanhf(ay * inv + g4.y);
  float o2 = tanhf(az * inv + g4.z), o3 = tanhf(aw * inv + g4.w);
  ushort4 h4, l4;
  f2hilo(o0, h4.x, l4.x); f2hilo(o1, h4.y, l4.y);
  f2hilo(o2, h4.z, l4.z); f2hilo(o3, h4.w, l4.w);
  *(ushort4*)(xbH + (size_t)j * 256 + lane * 4) = h4;
  *(ushort4*)(xbL + (size_t)j * 256 + lane * 4) = l4;
}

extern "C" void kernel_launch(void* const* d_in, const int* in_sizes, int n_in,
                              void* d_out, int out_size, void* d_ws, size_t ws_size,
                              hipStream_t stream){
  const float* feats   = (const float*)d_in[0];
  const float* Win     = (const float*)d_in[1];
  const float* b_in    = (const float*)d_in[2];
  const float* Wsrc    = (const float*)d_in[3];
  const float* Wdst    = (const float*)d_in[4];
  const float* att_src = (const float*)d_in[5];
  const float* att_dst = (const float*)d_in[6];
  const float* gat_b   = (const float*)d_in[7];
  const float* W_ih    = (const float*)d_in[8];
  const float* W_hh    = (const float*)d_in[9];
  const float* Wout    = (const float*)d_in[10];
  const float* b_out   = (const float*)d_in[11];
  const int* srcs[3] = {(const int*)d_in[12], (const int*)d_in[14], (const int*)d_in[16]};
  const int* dsts[3] = {(const int*)d_in[13], (const int*)d_in[15], (const int*)d_in[17]};
  (void)in_sizes; (void)n_in; (void)out_size; (void)ws_size;

  const int ns_a[3] = {60000, 30000, 15000};
  const int nd_a[3] = {30000, 15000, 7500};
  const int E_a[3]  = {480000, 240000, 120000};

  // ---- workspace layout (~229 MiB), aliasing lifetime-checked ----
  char* w = (char*)d_ws;
  float* xs    = (float*)(w + 0);                 // [60000][256] f32
  u16* featsH  = (u16*)(w + 0);                   // alias: dead before xs written
  u16* featsL  = (u16*)(w + 30720000);
  u16* x0H     = (u16*)(w + 61440000);            // hop-0 x hi/lo
  u16* x0L     = (u16*)(w + 92160000);
  float* c     = (float*)(w + 61440000);          // alias x0H: first write (hop0 epi) after x0 dead
  u16* hAH     = (u16*)(w + 122880000);           // h ping-pong set A
  u16* hAL     = (u16*)(w + 138240000);
  u16* hBH     = (u16*)(w + 153600000);           // set B
  u16* hBL     = (u16*)(w + 168960000);
  u16* xbH     = (u16*)(w + 184320000);
  u16* xbL     = (u16*)(w + 199680000);
  u16* WinH = (u16*)(w + 215040000);  u16* WinL = WinH + 32768;
  u16* WsH  = WinL + 32768;           u16* WsL  = WsH + 196608;
  u16* IhH  = WsL + 196608;           u16* IhL  = IhH + 786432;
  u16* HhH  = IhL + 786432;           u16* HhL  = HhH + 786432;
  u16* WoH  = HhL + 786432;           u16* WoL  = WoH + 32768;
  float* wsv = (float*)(WoL + 32768); float* wdv = wsv + 768;
  float* alpha_s    = wdv + 768;
  float* alpha_d    = alpha_s + 60000;
  float* alpha_e    = alpha_d + 30000;
  float* alpha_self = alpha_e + 480000;
  unsigned* amax    = (unsigned*)(alpha_self + 30000);
  int* cnt          = (int*)(amax + 30000);
  int* base         = cnt + 30000;
  int* cursor       = base + 30000;
  int* part         = cursor + 30000;             // scan partials (<=128)
  int* csr_src      = part + 256;
  float* csr_e      = (float*)(csr_src + 480000);

  // ---- one-time prep (inputs only) ----
  prep_w<<<7168, 256, 0, stream>>>(Win, Wsrc, W_ih, W_hh, Wout,
      WinH, WinL, WsH, WsL, IhH, IhL, HhH, HhL, WoH, WoL);
  prep_wvec<<<384, 256, 0, stream>>>(Wsrc, Wdst, att_src, att_dst, wsv, wdv);
  cvt_feats<<<7500, 256, 0, stream>>>(feats, featsH, featsL, 1920000);

  // ---- input projection: x0(hi/lo) = feats @ Win + b_in ----
  {
    dim3 g(2, CDIV(60000, 128));
    mfma_gemm<<<g, 256, 0, stream>>>(featsH, featsL, WinH, WinL,
        nullptr, nullptr, nullptr, nullptr, 1, 60000, 256, 128,
        b_in, nullptr, x0H, x0L, nullptr, nullptr, nullptr, nullptr, 0);
  }

  const u16* xHp = x0H; const u16* xLp = x0L;
  u16* hCurH = hAH; u16* hCurL = hAL;   // h produced by previous hop (input to pair1)
  u16* hNewH = hAH; u16* hNewL = hAL;   // h written this hop
  for (int hop = 0; hop < 3; hop++){
    const int ns = ns_a[hop], nd = nd_a[hop], E = E_a[hop];
    const int nb = CDIV(nd, 256);
    hipMemsetAsync(amax, 0, (size_t)(30000 + nd) * 4, stream);  // amax[30000] + cnt[0..nd)

    // xs = x @ Wsrc[hop]   (f32 out, feeds gather)
    {
      dim3 g(2, CDIV(ns, 128));
      mfma_gemm<<<g, 256, 0, stream>>>(xHp, xLp, WsH + (size_t)hop * 65536, WsL + (size_t)hop * 65536,
          nullptr, nullptr, nullptr, nullptr, 1, ns, 256, 256,
          nullptr, xs, nullptr, nullptr, nullptr, nullptr, nullptr, nullptr, 0);
    }
    alpha_mv<<<CDIV(ns + nd, 4), 256, 0, stream>>>(xHp, xLp, wsv + hop * 256, wdv + hop * 256,
        alpha_s, alpha_d, ns, nd);
    edge_a<<<CDIV(E + nd, 256), 256, 0, stream>>>(srcs[hop], dsts[hop], alpha_s, alpha_d,
        alpha_e, alpha_self, amax, cnt, E, nd);
    scan_part<<<nb, 256, 0, stream>>>(cnt, part, nd);
    scan_tot<<<1, 64, 0, stream>>>(part, nb);
    scan_fin<<<nb, 256, 0, stream>>>(cnt, part, base, cursor, nd);
    edge_b<<<CDIV(E, 256), 256, 0, stream>>>(srcs[hop], dsts[hop], alpha_e, amax,
        cursor, csr_src, csr_e, E);
    gather_xb<<<CDIV(nd, 4), 256, 0, stream>>>(xs, base, cnt, csr_src, csr_e,
        alpha_self, amax, gat_b + hop * 256, xbH, xbL, nd);

    // gates GEMM with fused LSTM epilogue; h double-buffered (epilogue write vs pair1 read)
    hNewH = (hop == 0) ? hAH : (hCurH == hAH ? hBH : hAH);
    hNewL = (hop == 0) ? hAL : (hCurL == hAL ? hBL : hAL);
    {
      dim3 g(8, CDIV(nd, 128));
      mfma_gemm<<<g, 256, 0, stream>>>(xbH, xbL, IhH + (size_t)hop * 262144, IhL + (size_t)hop * 262144,
          hCurH, hCurL, HhH + (size_t)hop * 262144, HhL + (size_t)hop * 262144,
          hop ? 2 : 1, nd, 1024, 256,
          nullptr, nullptr, nullptr, nullptr,
          c, c, hNewH, hNewL, hop == 0 ? 1 : 0);
    }
    hCurH = hNewH; hCurL = hNewL;
    xHp = hNewH; xLp = hNewL;
  }

  // ---- output projection: d_out = h @ Wout + b_out ----
  {
    dim3 g(1, CDIV(7500, 128));
    mfma_gemm<<<g, 256, 0, stream>>>(hCurH, hCurL, WoH, WoL,
        nullptr, nullptr, nullptr, nullptr, 1, 7500, 128, 256,
        b_out, (float*)d_out, nullptr, nullptr, nullptr, nullptr, nullptr, nullptr, 0);
  }
}